// Round 7
// baseline (330.102 us; speedup 1.0000x reference)
//
#include <hip/hip_runtime.h>

#define NN 256
#define CC 16
#define OC 288          // 18*16 output channels (72 float4)
#define DMAX 128        // neighbor-list cap (deg ~31±5; 128 = +18σ, never hit)

typedef unsigned long long u64;
typedef unsigned char u8;

__device__ __forceinline__ void add4(float4& a, const float4 b) {
    a.x += b.x; a.y += b.y; a.z += b.z; a.w += b.w;
}

// ---------------- K0: neighbor lists as u8 (byte indices) ----------------
__global__ void k_build_nbr(const float* __restrict__ A, u8* __restrict__ nbr8,
                            int* __restrict__ deg) {
    int a = blockIdx.x;
    int t = threadIdx.x;            // 0..255
    int lane = t & 63, wave = t >> 6;
    bool pred = A[a*NN + t] != 0.0f;
    u64 m = __ballot(pred);
    __shared__ int wcnt[4];
    if (lane == 0) wcnt[wave] = __popcll(m);
    __syncthreads();
    int off = 0;
    for (int w = 0; w < wave; ++w) off += wcnt[w];
    if (pred) {
        int pos = off + __popcll(m & ((1ull << lane) - 1ull));
        if (pos < DMAX) nbr8[a*DMAX + pos] = (u8)t;
    }
    if (t == 0) {
        int d = wcnt[0] + wcnt[1] + wcnt[2] + wcnt[3];
        deg[a] = d < DMAX ? d : DMAX;
    }
}

// ---------------- K_slab4: c1,c2,c3,c4 + c7..c12 (slab p) ----------------
// 256 blocks x 1024 threads (2 blocks/CU). Full neighbor table staged in LDS
// (u8, 32 KB) -> gather indices are LDS byte reads, no global dependent chain.
// Phase A: c3 dense rows (fully coalesced, register acc) + c7/c8 from row (p,p).
// Phase B: group g (4 lanes) owns row (p,g):
//   loop nbl[p]: c1[p,g] register reduce   (uniform index -> scalarizable)
//   loop nbl[g]: c2[g,p] register reduce AND c4[k,p] via LDS float atomics
//                (identical chunk set -> c4 costs zero extra fetch)
//   2 diag chunks -> c9,c10,c11,c12.
__global__ __launch_bounds__(1024, 2) void k_slab4(const float4* __restrict__ T4,
                                                   const u8* __restrict__ nbr8,
                                                   const int* __restrict__ deg,
                                                   float4* __restrict__ out4) {
    const int p = blockIdx.x;
    const int t = threadIdx.x;
    const int g = t >> 2, v = t & 3;

    __shared__ u8    nbl[NN][DMAX];      // 32 KB
    __shared__ int   degl[NN];           // 1 KB
    __shared__ float c4a[NN*17];         // 17 KB (stride 17 floats: bank spread)

    for (int idx = t; idx < NN*DMAX/16; idx += 1024)
        ((uint4*)nbl)[idx] = ((const uint4*)nbr8)[idx];
    if (t < NN) degl[t] = deg[t];
    for (int idx = t; idx < NN*17; idx += 1024) c4a[idx] = 0.f;
    __syncthreads();

    const int dp = degl[p];
    const float4* slab = T4 + ((size_t)p << 18);

    // ---- Phase A: c3 (dense rows j in N(p)) + c7/c8 (row (p,p)) ----
    {
        float4 acc3 = {0,0,0,0};
        #pragma unroll 2
        for (int e = 0; e < dp; ++e) {
            int jj = nbl[p][e];                       // block-uniform
            add4(acc3, slab[((size_t)jj << 10) + t]); // fully coalesced
        }
        int b = t >> 2, vv = t & 3;
        out4[(size_t)(p*NN + b)*72 + 8 + vv] = acc3;  // c3[p,b]

        float4 xpp = slab[((size_t)p << 10) + t];     // T[p,p,b,:]
        out4[(size_t)(p*NN + b)*72 + 24 + vv] = xpp;  // c7[p,b]
        out4[(size_t)(b*NN + p)*72 + 28 + vv] = xpp;  // c8[b,p]
    }

    // ---- Phase B: per-row gathers ----
    const float4* row = slab + ((size_t)g << 10);     // row (p, g)
    const int dg = degl[g];

    float4 a1 = {0,0,0,0};
    #pragma unroll 4
    for (int e = 0; e < dp; ++e) {
        int k = nbl[p][e];                            // uniform
        add4(a1, row[(k << 2) + v]);
    }

    float4 a2 = {0,0,0,0};
    float* c4base = &c4a[0] + v*4;
    #pragma unroll 4
    for (int e = 0; e < dg; ++e) {
        int k = nbl[g][e];                            // LDS byte read (per-group)
        float4 x = row[(k << 2) + v];
        add4(a2, x);
        float* cp = c4base + k*17;
        atomicAdd(cp+0, x.x); atomicAdd(cp+1, x.y);
        atomicAdd(cp+2, x.z); atomicAdd(cp+3, x.w);
    }

    float4 xP = row[(p << 2) + v];                    // T[p,g,p,:]
    float4 xJ = row[(g << 2) + v];                    // T[p,g,g,:]
    size_t opg = (size_t)(p*NN + g) * 72;
    size_t ogp = (size_t)(g*NN + p) * 72;
    out4[opg + 0  + v] = a1;    // c1[p,g]
    out4[ogp + 4  + v] = a2;    // c2[g,p]
    out4[opg + 32 + v] = xP;    // c9 [p,g] = T[p,g,p]
    out4[ogp + 36 + v] = xP;    // c10[g,p] = T[p,g,p]
    out4[opg + 40 + v] = xJ;    // c11[p,g] = T[p,g,g]
    out4[ogp + 44 + v] = xJ;    // c12[g,p] = T[p,g,g]

    __syncthreads();
    // flush c4[.,p]
    for (int idx = t; idx < NN*4; idx += 1024) {
        int k = idx >> 2, vv = idx & 3;
        float4 x4 = {c4a[k*17+vv*4+0], c4a[k*17+vv*4+1],
                     c4a[k*17+vv*4+2], c4a[k*17+vv*4+3]};
        out4[(size_t)(k*NN + p)*72 + 12 + vv] = x4;
    }
}

// ---------------- K_col56: c5 (contiguous) + c6 (gather) — R2's proven k_col ----
__global__ __launch_bounds__(256) void k_col56(const float4* __restrict__ T4,
                                               const u8* __restrict__ nbr8,
                                               const int* __restrict__ deg,
                                               float4* __restrict__ out4) {
    int a = blockIdx.x >> 2;
    int qq = blockIdx.x & 3;
    int t = threadIdx.x;
    int g = t >> 2, v = t & 3;
    int d = deg[a];
    __shared__ short nbs[DMAX];
    for (int e = t; e < d; e += 256) nbs[e] = (short)nbr8[a*DMAX + e];
    __syncthreads();

    const int b = qq*64 + g;
    const int qslot = qq*256 + t;        // = (b<<2)+v
    float4 a5 = {0,0,0,0};
    float4 a6 = {0,0,0,0};
    #pragma unroll 2
    for (int e = 0; e < d; ++e) {
        int i = nbs[e];
        float4 x5 = T4[((size_t)(i*NN + a) << 10) + qslot];           // T[i,a,b,:]
        float4 x6 = T4[((size_t)(i*NN + b) << 10) + (a << 2) + v];    // T[i,b,a,:]
        add4(a5, x5); add4(a6, x6);
    }
    size_t o = (size_t)(a*NN + b) * 72;
    out4[o + 16 + v] = a5;    // c5
    out4[o + 20 + v] = a6;    // c6
}

// ---------------- K_V: v1,v2,v3 from materialized c1,c2,c4 ----------------
// v1[a]=sum_{b in N(a)} c1[a,b]; v2 from c2; v3 from c4 (identity:
// v3[a]=sum_{i,j in N(a)} T[i,j,a] = sum_{b in N(a)} c4[a,b]).
__global__ void k_vsum(const float* __restrict__ out_ro,
                       const u8* __restrict__ nbr8, const int* __restrict__ deg,
                       float* __restrict__ vbuf) {
    int a = blockIdx.x;
    int t = threadIdx.x;            // 256
    int c = t & 15, p = t >> 4;
    int d = deg[a];
    float s1 = 0.f, s2 = 0.f, s3 = 0.f;
    for (int e = p; e < d; e += 16) {
        int b = nbr8[a*DMAX + e];
        size_t o = (size_t)(a*NN + b) * OC;
        s1 += out_ro[o + 0  + c];   // c1
        s2 += out_ro[o + 16 + c];   // c2
        s3 += out_ro[o + 48 + c];   // c4
    }
    __shared__ float red[3][16][17];
    red[0][p][c] = s1; red[1][p][c] = s2; red[2][p][c] = s3;
    __syncthreads();
    if (t < 48) {
        int vv = t >> 4, cc = t & 15;
        float s = 0.f;
        for (int pp = 0; pp < 16; ++pp) s += red[vv][pp][cc];
        vbuf[(vv*NN + a)*CC + cc] = s;
    }
}

// ---------------- K_C: broadcast v's into channels 12..17 ----------------
__global__ __launch_bounds__(256) void k_broadcast(const float4* __restrict__ vb4,
                                                   float4* __restrict__ out4) {
    int a = blockIdx.x;
    int t = threadIdx.x;
    int v = t & 3, bl = t >> 2;
    float4 v1a = vb4[(0*NN + a)*4 + v];
    float4 v2a = vb4[(1*NN + a)*4 + v];
    float4 v3a = vb4[(2*NN + a)*4 + v];
    for (int b = bl; b < NN; b += 64) {
        float4 v1b = vb4[(0*NN + b)*4 + v];
        float4 v2b = vb4[(1*NN + b)*4 + v];
        float4 v3b = vb4[(2*NN + b)*4 + v];
        size_t ob = (size_t)(a*NN + b) * 72;
        out4[ob + 48 + v] = v1a;   // c13
        out4[ob + 52 + v] = v1b;   // c14
        out4[ob + 56 + v] = v2a;   // c15
        out4[ob + 60 + v] = v2b;   // c16
        out4[ob + 64 + v] = v3a;   // c17
        out4[ob + 68 + v] = v3b;   // c18
    }
}

extern "C" void kernel_launch(void* const* d_in, const int* in_sizes, int n_in,
                              void* d_out, int out_size, void* d_ws, size_t ws_size,
                              hipStream_t stream) {
    const float* T = (const float*)d_in[0];   // (256,256,256,16) f32
    const float* A = (const float*)d_in[1];   // (256,256) f32 {0,1} symmetric
    float* out = (float*)d_out;

    // ws: nbr8 u8[256*128] | deg int[256] | vbuf f32[3*256*16]
    char* w = (char*)d_ws;
    u8*  nbr8 = (u8*)w;                       w += NN*DMAX*sizeof(u8);
    int* deg  = (int*)w;                      w += NN*sizeof(int);
    float* vbuf = (float*)w;

    hipLaunchKernelGGL(k_build_nbr, dim3(NN),   dim3(NN),   0, stream, A, nbr8, deg);
    hipLaunchKernelGGL(k_slab4,     dim3(NN),   dim3(1024), 0, stream,
                       (const float4*)T, nbr8, deg, (float4*)out);
    hipLaunchKernelGGL(k_col56,     dim3(NN*4), dim3(256),  0, stream,
                       (const float4*)T, nbr8, deg, (float4*)out);
    hipLaunchKernelGGL(k_vsum,      dim3(NN),   dim3(256),  0, stream, out, nbr8, deg, vbuf);
    hipLaunchKernelGGL(k_broadcast, dim3(NN),   dim3(256),  0, stream,
                       (const float4*)vbuf, (float4*)out);
}

// Round 8
// 233.415 us; speedup vs baseline: 1.4142x; 1.4142x over previous
//
#include <hip/hip_runtime.h>

#define NN 256
#define CC 16
#define NC (NN*CC)      // 4096 floats per (i,j) row
#define OC (18*CC)      // 288 output channels (72 float4)

__device__ __forceinline__ void add4(float4& a, const float4 b) {
    a.x += b.x; a.y += b.y; a.z += b.z; a.w += b.w;
}
__device__ __forceinline__ void mad4(float4& a, const float4 b, float m) {
    a.x += b.x*m; a.y += b.y*m; a.z += b.z*m; a.w += b.w*m;
}

// ---------------- K0: neighbor lists (ballot compaction) ----------------
__global__ void k_build_nbr(const float* __restrict__ A, short* __restrict__ nbr,
                            int* __restrict__ deg) {
    int a = blockIdx.x;
    int t = threadIdx.x;            // 0..255
    int lane = t & 63, wave = t >> 6;
    bool pred = A[a*NN + t] != 0.0f;
    unsigned long long m = __ballot(pred);
    __shared__ int wcnt[4];
    if (lane == 0) wcnt[wave] = __popcll(m);
    __syncthreads();
    int off = 0;
    for (int w = 0; w < wave; ++w) off += wcnt[w];
    if (pred) {
        int pos = off + __popcll(m & ((1ull << lane) - 1ull));
        nbr[a*NN + pos] = (short)t;
    }
    if (t == 0) deg[a] = wcnt[0] + wcnt[1] + wcnt[2] + wcnt[3];
}

// ---------------- K1: fused c1..c12 + v-partials ----------------
// block = (a, quarter q of b); thread: v = t&3 (float4 slot), bl = t>>2, b = q*64+bl.
// All loads are float4 (64B per 4 lanes, coalesced). Writes cover out[.., 0:192)
// contiguously. v1/v2/v3 partial sums over b in this quarter go to vpart.
__global__ __launch_bounds__(256) void k_fused(const float4* __restrict__ T4,
                                               const float* __restrict__ A,
                                               const short* __restrict__ nbr,
                                               const int* __restrict__ deg,
                                               float4* __restrict__ out4,
                                               float* __restrict__ vpart) {
    int a = blockIdx.x >> 2;
    int q = blockIdx.x & 3;
    int t = threadIdx.x;
    int v = t & 3, bl = t >> 2;
    int b = q*64 + bl;
    int d = deg[a];

    __shared__ short nbs[NN];
    __shared__ float red[3][64][16];
    for (int e = t; e < d; e += 256) nbs[e] = nbr[a*NN + e];
    __syncthreads();

    // float4-unit row bases (1024 float4 per (i,j) row)
    const int rowAB = (a*NN + b) << 10;
    const int rowBA = (b*NN + a) << 10;
    const int slabA = a << 18;          // (a*NN)<<10
    const int slabB = b << 18;
    const int offB  = (b << 2) + v;     // chunk offset b*4+v inside a row
    const int offA  = (a << 2) + v;

    float4 z = make_float4(0.f,0.f,0.f,0.f);
    float4 acc1=z, acc2=z, acc3=z, acc4=z, acc5=z, acc6=z;
    #pragma unroll 2
    for (int e = 0; e < d; ++e) {
        int k = nbs[e];
        float4 x1 = T4[rowAB + (k<<2) + v];          // T[a,b,k,:]
        float4 x2 = T4[rowBA + (k<<2) + v];          // T[b,a,k,:]
        float4 x3 = T4[slabA + (k<<10) + offB];      // T[a,k,b,:]
        float4 x4 = T4[slabB + (k<<10) + offA];      // T[b,k,a,:]
        float4 x5 = T4[(k<<18) + (a<<10) + offB];    // T[k,a,b,:]
        float4 x6 = T4[(k<<18) + (b<<10) + offA];    // T[k,b,a,:]
        add4(acc1,x1); add4(acc2,x2); add4(acc3,x3);
        add4(acc4,x4); add4(acc5,x5); add4(acc6,x6);
    }

    // diagonals
    float4 d7  = T4[slabA + (a<<10) + offB];   // T[a,a,b,:]
    float4 d8  = T4[slabB + (b<<10) + offA];   // T[b,b,a,:]
    float4 d9  = T4[rowAB + offA];             // T[a,b,a,:]
    float4 d10 = T4[rowBA + offB];             // T[b,a,b,:]
    float4 d11 = T4[rowAB + offB];             // T[a,b,b,:]
    float4 d12 = T4[rowBA + offA];             // T[b,a,a,:]

    // write channels 0..11 : contiguous [0,192) bytes of the output row
    const int ob = (a*NN + b)*72;
    out4[ob + 0*4 + v] = acc1;
    out4[ob + 1*4 + v] = acc2;
    out4[ob + 2*4 + v] = acc3;
    out4[ob + 3*4 + v] = acc4;
    out4[ob + 4*4 + v] = acc5;
    out4[ob + 5*4 + v] = acc6;
    out4[ob + 6*4 + v] = d7;
    out4[ob + 7*4 + v] = d8;
    out4[ob + 8*4 + v] = d9;
    out4[ob + 9*4 + v] = d10;
    out4[ob +10*4 + v] = d11;
    out4[ob +11*4 + v] = d12;

    // v-partials: v1[a]=sum_{b in N(a)} c1[a,b]; v2 from c2; v3 from c6
    float m = (A[a*NN + b] != 0.0f) ? 1.0f : 0.0f;
    float4 m1=z, m2=z, m3=z;
    mad4(m1, acc1, m); mad4(m2, acc2, m); mad4(m3, acc6, m);
    red[0][bl][v*4+0]=m1.x; red[0][bl][v*4+1]=m1.y; red[0][bl][v*4+2]=m1.z; red[0][bl][v*4+3]=m1.w;
    red[1][bl][v*4+0]=m2.x; red[1][bl][v*4+1]=m2.y; red[1][bl][v*4+2]=m2.z; red[1][bl][v*4+3]=m2.w;
    red[2][bl][v*4+0]=m3.x; red[2][bl][v*4+1]=m3.y; red[2][bl][v*4+2]=m3.z; red[2][bl][v*4+3]=m3.w;
    __syncthreads();
    if (t < 48) {
        int vi = t >> 4, cc = t & 15;
        float s = 0.f;
        for (int i = 0; i < 64; ++i) s += red[vi][i][cc];
        vpart[((a*4 + q)*3 + vi)*CC + cc] = s;
    }
}

// ---------------- K2: sum quarter partials -> vbuf ----------------
__global__ void k_vred(const float* __restrict__ vpart, float* __restrict__ vbuf) {
    int idx = blockIdx.x*256 + threadIdx.x;   // 0..12287
    int vi = idx >> 12, rem = idx & 4095;
    int a = rem >> 4, cc = rem & 15;
    float s = 0.f;
    for (int q = 0; q < 4; ++q) s += vpart[((a*4 + q)*3 + vi)*CC + cc];
    vbuf[(vi*NN + a)*CC + cc] = s;
}

// ---------------- K3: broadcast v's into channels 12..17 ----------------
__global__ __launch_bounds__(256) void k_broadcast(const float4* __restrict__ vb4,
                                                   float4* __restrict__ out4) {
    int a = blockIdx.x;
    int t = threadIdx.x;
    int v = t & 3, bl = t >> 2;
    float4 v1a = vb4[(0*NN + a)*4 + v];
    float4 v2a = vb4[(1*NN + a)*4 + v];
    float4 v3a = vb4[(2*NN + a)*4 + v];
    for (int b = bl; b < NN; b += 64) {
        float4 v1b = vb4[(0*NN + b)*4 + v];
        float4 v2b = vb4[(1*NN + b)*4 + v];
        float4 v3b = vb4[(2*NN + b)*4 + v];
        int ob = (a*NN + b)*72;
        out4[ob + 48 + v] = v1a;   // c13
        out4[ob + 52 + v] = v1b;   // c14
        out4[ob + 56 + v] = v2a;   // c15
        out4[ob + 60 + v] = v2b;   // c16
        out4[ob + 64 + v] = v3a;   // c17
        out4[ob + 68 + v] = v3b;   // c18
    }
}

extern "C" void kernel_launch(void* const* d_in, const int* in_sizes, int n_in,
                              void* d_out, int out_size, void* d_ws, size_t ws_size,
                              hipStream_t stream) {
    const float* T = (const float*)d_in[0];   // (256,256,256,16) f32
    const float* A = (const float*)d_in[1];   // (256,256) f32 {0,1} symmetric
    float* out = (float*)d_out;

    // ws layout: nbr short[256*256] | deg int[256] | vpart f32[256*4*3*16] | vbuf f32[3*256*16]
    char* w = (char*)d_ws;
    short* nbr  = (short*)w;                          w += NN*NN*sizeof(short);
    int*   deg  = (int*)w;                            w += NN*sizeof(int);
    float* vpart= (float*)w;                          w += NN*4*3*CC*sizeof(float);
    float* vbuf = (float*)w;

    hipLaunchKernelGGL(k_build_nbr, dim3(NN),   dim3(NN),  0, stream, A, nbr, deg);
    hipLaunchKernelGGL(k_fused,     dim3(NN*4), dim3(256), 0, stream,
                       (const float4*)T, A, nbr, deg, (float4*)out, vpart);
    hipLaunchKernelGGL(k_vred,      dim3(48),   dim3(256), 0, stream, vpart, vbuf);
    hipLaunchKernelGGL(k_broadcast, dim3(NN),   dim3(256), 0, stream,
                       (const float4*)vbuf, (float4*)out);
}